// Round 17
// baseline (120.302 us; speedup 1.0000x reference)
//
#include <hip/hip_runtime.h>

#define HID    128
#define VOCAB  1000
#define N_CAT  200000
#define N_CONT 150000
#define N_TXN  150000
#define F_TXN  371
#define KP     384                           // padded K in workspace B^T
#define NSTEP  12                            // 12*32 = 384 >= 371
#define OUT_TXN_BASE (N_CAT + N_CONT)

#define SLAB_ROWS   16
#define SLAB_F32    (SLAB_ROWS * F_TXN)      // 5936 floats = 1484 x 16B chunks exactly
#define SLAB_CHUNKS (SLAB_F32 / 4)           // 1484
#define LROW        392                      // LDS row stride (shorts), odd 16B-chunk count
#define SLAB_SHORTS (SLAB_ROWS * LROW)       // 6272 shorts = 12544 B
#define NSLAB       (N_TXN / SLAB_ROWS)      // 9375 exactly
#define PBLK        512                      // txn blocks: 2/CU (proven best)
#define CLSLAB(x)   ((x) < NSLAB ? (x) : (NSLAB - 1))

#define CAT_BLOCKS  (N_CAT / 8)              // 25000
#define CONT_BLOCKS (N_CONT / 8)             // 18750
#define GRID_TOTAL  (PBLK + CAT_BLOCKS + CONT_BLOCKS)

typedef __attribute__((ext_vector_type(4))) float f32x4;
typedef __attribute__((ext_vector_type(8))) short bf16x8;

__device__ __forceinline__ unsigned short f2bf(float x) {
    union { float f; unsigned u; } c; c.f = x;
    unsigned r = c.u + 0x7FFF + ((c.u >> 16) & 1);   // RNE
    return (unsigned short)(r >> 16);
}

// ---- producer: Bt[col][k] = bf16(w[k][col]), zero-padded to KP ----
__global__ void bt_kernel(const float* __restrict__ w, unsigned short* __restrict__ bt) {
    int col = blockIdx.x;          // 0..127
    int k   = threadIdx.x;         // 0..383
    float v = (k < F_TXN) ? w[(long)k * HID + col] : 0.f;
    bt[col * KP + k] = f2bf(v);
}

// ---- spatially-fused kernel: blocks [0,PBLK) = persistent txn GEMM;
//      blocks [PBLK, ...) = cat/cont streaming with NT stores.
// txn reads (L3-resident A) and catcont writes (NT->HBM) use disjoint
// resources, so co-residency overlaps the two phases. NT stores keep the
// 256 MB output stream from evicting A out of Infinity Cache (round-15 win).
__global__ __launch_bounds__(256) void fused_kernel(
    const float* __restrict__ tables, const int* __restrict__ tids, const int* __restrict__ vids,
    const float* __restrict__ cw, const float* __restrict__ cb,
    const float* __restrict__ vals, const int* __restrict__ ctids,
    const float* __restrict__ feats, const unsigned short* __restrict__ bt,
    const float* __restrict__ bias, float* __restrict__ out)
{
    __shared__ __align__(16) unsigned short Alds[2 * SLAB_SHORTS];   // 25088 B

    if (blockIdx.x >= PBLK) {
        // ================= cat / cont streaming (NT stores) =================
        int bid = blockIdx.x - PBLK;
        if (bid < CAT_BLOCKS) {
            int tid = bid * 256 + threadIdx.x;
            int row = tid >> 5;
            int h   = (tid & 31) << 2;
            long src = ((long)tids[row] * VOCAB + vids[row]) * HID + h;
            f32x4 v = *reinterpret_cast<const f32x4*>(tables + src);
            __builtin_nontemporal_store(v, reinterpret_cast<f32x4*>(out + (long)row * HID + h));
        } else {
            int tid = (bid - CAT_BLOCKS) * 256 + threadIdx.x;
            int row = tid >> 5;
            int h   = (tid & 31) << 2;
            int ty  = ctids[row];
            float v = vals[row];
            f32x4 wv = *reinterpret_cast<const f32x4*>(cw + ty * HID + h);
            f32x4 bv = *reinterpret_cast<const f32x4*>(cb + ty * HID + h);
            f32x4 r  = v * wv + bv;
            __builtin_nontemporal_store(r, reinterpret_cast<f32x4*>(out + (long)(N_CAT + row) * HID + h));
        }
        return;
    }

    // ================= persistent txn GEMM (round-15 proven) =================
    const int t    = threadIdx.x;
    const int lane = t & 63;
    const int w    = t >> 6;
    const int r16  = lane & 15;
    const int kg   = lane >> 4;

    // ---- B fragments into registers, once per block ----
    bf16x8 Bf0[NSTEP], Bf1[NSTEP];
    float bv0, bv1;
    {
        int c0 = w * 32 + r16, c1 = c0 + 16;
        bv0 = bias[c0]; bv1 = bias[c1];
        const unsigned short* p0 = bt + (size_t)c0 * KP + kg * 8;
        const unsigned short* p1 = bt + (size_t)c1 * KP + kg * 8;
        #pragma unroll
        for (int s = 0; s < NSTEP; ++s) {
            Bf0[s] = *reinterpret_cast<const bf16x8*>(p0 + s * 32);
            Bf1[s] = *reinterpret_cast<const bf16x8*>(p1 + s * 32);
        }
    }

    // ---- fixed staging geometry: thread t owns chunks q = i*256+t (16B each) ----
    bool sval[6];
    unsigned wa0[6], wa1[6];                 // packed LDS short-addresses
    #pragma unroll
    for (int i = 0; i < 6; ++i) {
        int q = i * 256 + t;
        sval[i] = (q < SLAB_CHUNKS);
        int qq = sval[i] ? q : 0;
        unsigned a[4];
        #pragma unroll
        for (int j = 0; j < 4; ++j) {
            int e   = qq * 4 + j;            // float index within slab
            int r   = e / F_TXN;
            int col = e - r * F_TXN;
            a[j] = (unsigned)(r * LROW + col);
        }
        wa0[i] = a[0] | (a[1] << 16);
        wa1[i] = a[2] | (a[3] << 16);
    }

    // ---- zero never-written cols 371..383 (read at s=11; B=0 there) ----
    for (int z = t; z < 2 * SLAB_ROWS * (KP - F_TXN); z += 256) {
        int b  = z / (SLAB_ROWS * (KP - F_TXN));
        int rm = z - b * (SLAB_ROWS * (KP - F_TXN));
        int r  = rm / (KP - F_TXN);
        int cc = rm - r * (KP - F_TXN);
        Alds[b * SLAB_SHORTS + r * LROW + F_TXN + cc] = 0;
    }

    f32x4 arA[6], arB[6];

    auto gload = [&](f32x4 (&ar)[6], int sl) {
        size_t S0 = (size_t)sl * SLAB_F32;   // 16B-aligned, exactly 1484 chunks
        #pragma unroll
        for (int i = 0; i < 6; ++i)
            if (sval[i])
                ar[i] = *reinterpret_cast<const f32x4*>(feats + S0 + (size_t)(i * 256 + t) * 4);
    };
    auto swrite = [&](int buf, const f32x4 (&ar)[6]) {
        unsigned short* dst = Alds + buf * SLAB_SHORTS;
        #pragma unroll
        for (int i = 0; i < 6; ++i)
            if (sval[i]) {
                dst[wa0[i] & 0xffffu] = f2bf(ar[i][0]);
                dst[wa0[i] >> 16]     = f2bf(ar[i][1]);
                dst[wa1[i] & 0xffffu] = f2bf(ar[i][2]);
                dst[wa1[i] >> 16]     = f2bf(ar[i][3]);
            }
    };

    const int bid = blockIdx.x;
    int sl  = bid;
    int cur = 0;

    // prologue: LDS[0] = slab bid; arA = slab bid+P in flight
    gload(arA, sl);
    swrite(0, arA);
    gload(arA, CLSLAB(sl + PBLK));
    __syncthreads();

    auto iter = [&](const f32x4 (&pend)[6], f32x4 (&tgt)[6]) {
        gload(tgt, CLSLAB(sl + 2 * PBLK));        // keep >=6 loads outstanding always
        __builtin_amdgcn_sched_barrier(0);        // don't sink below the vmcnt wait

        f32x4 acc0 = f32x4{0.f, 0.f, 0.f, 0.f};
        f32x4 acc1 = f32x4{0.f, 0.f, 0.f, 0.f};
        const unsigned short* Ar = Alds + cur * SLAB_SHORTS + r16 * LROW;
        #pragma unroll
        for (int s = 0; s < NSTEP; ++s) {         // conflict-free b128 reads
            bf16x8 af = *reinterpret_cast<const bf16x8*>(Ar + s * 32 + kg * 8);
            acc0 = __builtin_amdgcn_mfma_f32_16x16x32_bf16(af, Bf0[s], acc0, 0, 0, 0);
            acc1 = __builtin_amdgcn_mfma_f32_16x16x32_bf16(af, Bf1[s], acc1, 0, 0, 0);
        }

        swrite(cur ^ 1, pend);                    // waits only pend's (older) loads

        long R0 = (long)sl * SLAB_ROWS + kg * 4;  // NT C-stores fly across the barrier
        int  c0 = w * 32 + r16;
        #pragma unroll
        for (int j = 0; j < 4; ++j) {
            float* o = out + (OUT_TXN_BASE + R0 + j) * HID;
            __builtin_nontemporal_store(acc0[j] + bv0, o + c0);
            __builtin_nontemporal_store(acc1[j] + bv1, o + c0 + 16);
        }

        asm volatile("s_waitcnt lgkmcnt(0)" ::: "memory");   // LDS writes visible
        __builtin_amdgcn_s_barrier();             // no vmcnt drain
        __builtin_amdgcn_sched_barrier(0);
        cur ^= 1;
        sl  += PBLK;
    };

    while (sl < NSLAB) {
        iter(arA, arB);
        if (sl >= NSLAB) break;
        iter(arB, arA);
    }
}

extern "C" void kernel_launch(void* const* d_in, const int* in_sizes, int n_in,
                              void* d_out, int out_size, void* d_ws, size_t ws_size,
                              hipStream_t stream) {
    const float* cat_tables    = (const float*)d_in[0];
    const float* cont_w        = (const float*)d_in[1];
    const float* cont_b        = (const float*)d_in[2];
    const float* txn_w         = (const float*)d_in[3];
    const float* txn_b         = (const float*)d_in[4];
    const float* txn_feats     = (const float*)d_in[5];
    const float* cont_values   = (const float*)d_in[6];
    const int*   cat_type_ids  = (const int*)d_in[7];
    const int*   cat_value_ids = (const int*)d_in[8];
    const int*   cont_type_ids = (const int*)d_in[9];
    float* out = (float*)d_out;
    unsigned short* bt = (unsigned short*)d_ws;   // 128*384*2 = 96 KB

    bt_kernel<<<HID, KP, 0, stream>>>(txn_w, bt);
    fused_kernel<<<GRID_TOTAL, 256, 0, stream>>>(
        cat_tables, cat_type_ids, cat_value_ids,
        cont_w, cont_b, cont_values, cont_type_ids,
        txn_feats, bt, txn_b, out);
}

// Round 18
// 84.357 us; speedup vs baseline: 1.4261x; 1.4261x over previous
//
#include <hip/hip_runtime.h>

#define HID    128
#define VOCAB  1000
#define N_CAT  200000
#define N_CONT 150000
#define N_TXN  150000
#define F_TXN  371
#define NSTEP  12                            // 12*32 = 384 >= 371
#define OUT_TXN_BASE (N_CAT + N_CONT)

#define SLAB_ROWS   16
#define SLAB_F32    (SLAB_ROWS * F_TXN)      // 5936 floats = 1484 x 16B chunks exactly
#define SLAB_CHUNKS (SLAB_F32 / 4)           // 1484
#define LROW        392                      // LDS row stride (shorts), odd 16B-chunk count
#define SLAB_SHORTS (SLAB_ROWS * LROW)       // 6272 shorts = 12544 B
#define NSLAB       (N_TXN / SLAB_ROWS)      // 9375 exactly
#define PBLK        512                      // 2 blocks/CU (proven best)
#define CLSLAB(x)   ((x) < NSLAB ? (x) : (NSLAB - 1))

typedef __attribute__((ext_vector_type(4))) float f32x4;
typedef __attribute__((ext_vector_type(8))) short bf16x8;

__device__ __forceinline__ unsigned short f2bf(float x) {
    union { float f; unsigned u; } c; c.f = x;
    unsigned r = c.u + 0x7FFF + ((c.u >> 16) & 1);   // RNE
    return (unsigned short)(r >> 16);
}

__device__ __forceinline__ unsigned cvt_pk(float lo, float hi) {
    unsigned r;
    asm("v_cvt_pk_bf16_f32 %0, %1, %2" : "=v"(r) : "v"(lo), "v"(hi));
    return r;
}

union BFrag { bf16x8 v; unsigned u[4]; };

// ---- fused cat gather + cont linear; NT stores keep out-stream out of L3 ----
#define CAT_BLOCKS  (N_CAT / 8)
#define CONT_BLOCKS (N_CONT / 8)
__global__ __launch_bounds__(256) void catcont_kernel(
    const float* __restrict__ tables, const int* __restrict__ tids, const int* __restrict__ vids,
    const float* __restrict__ w, const float* __restrict__ b,
    const float* __restrict__ vals, const int* __restrict__ ctids,
    float* __restrict__ out)
{
    int bid = blockIdx.x;
    if (bid < CAT_BLOCKS) {
        int tid = bid * 256 + threadIdx.x;
        int row = tid >> 5;
        int h   = (tid & 31) << 2;
        long src = ((long)tids[row] * VOCAB + vids[row]) * HID + h;
        f32x4 v = *reinterpret_cast<const f32x4*>(tables + src);
        __builtin_nontemporal_store(v, reinterpret_cast<f32x4*>(out + (long)row * HID + h));
    } else {
        int tid = (bid - CAT_BLOCKS) * 256 + threadIdx.x;
        int row = tid >> 5;
        int h   = (tid & 31) << 2;
        int t   = ctids[row];
        float v = vals[row];
        f32x4 wv = *reinterpret_cast<const f32x4*>(w + t * HID + h);
        f32x4 bv = *reinterpret_cast<const f32x4*>(b + t * HID + h);
        f32x4 r  = v * wv + bv;
        __builtin_nontemporal_store(r, reinterpret_cast<f32x4*>(out + (long)(N_CAT + row) * HID + h));
    }
}

// ---- persistent txn GEMM: inline B-build from txn_w, depth-2 reg prefetch,
//      dbuf bf16 LDS, NT C-stores (keep 256 MB out-stream from evicting A) ----
__global__ __launch_bounds__(256) void txn_persist_kernel(
    const float* __restrict__ feats, const float* __restrict__ txn_w,
    const float* __restrict__ bias, float* __restrict__ out)
{
    __shared__ __align__(16) unsigned short Alds[2 * SLAB_SHORTS];   // 25088 B

    const int t    = threadIdx.x;
    const int lane = t & 63;
    const int w    = t >> 6;
    const int r16  = lane & 15;
    const int kg   = lane >> 4;

    // ---- B fragments built inline from txn_w (f32, L2-hot 190 KB), once per block ----
    BFrag Bf0[NSTEP], Bf1[NSTEP];
    const int c0 = w * 32 + r16, c1 = c0 + 16;
    const float bv0 = bias[c0], bv1 = bias[c1];
    #pragma unroll
    for (int s = 0; s < NSTEP; ++s) {
        #pragma unroll
        for (int h = 0; h < 4; ++h) {
            int k = s * 32 + kg * 8 + h * 2;
            float w0 = (k     < F_TXN) ? txn_w[(long)k * HID + c0]       : 0.f;
            float w1 = (k + 1 < F_TXN) ? txn_w[(long)(k + 1) * HID + c0] : 0.f;
            Bf0[s].u[h] = cvt_pk(w0, w1);
            float x0 = (k     < F_TXN) ? txn_w[(long)k * HID + c1]       : 0.f;
            float x1 = (k + 1 < F_TXN) ? txn_w[(long)(k + 1) * HID + c1] : 0.f;
            Bf1[s].u[h] = cvt_pk(x0, x1);
        }
    }

    // ---- fixed staging geometry: thread t owns chunks q = i*256+t (16B each) ----
    bool sval[6];
    unsigned wa0[6], wa1[6];                 // packed LDS short-addresses
    #pragma unroll
    for (int i = 0; i < 6; ++i) {
        int q = i * 256 + t;
        sval[i] = (q < SLAB_CHUNKS);
        int qq = sval[i] ? q : 0;
        unsigned a[4];
        #pragma unroll
        for (int j = 0; j < 4; ++j) {
            int e   = qq * 4 + j;            // float index within slab
            int r   = e / F_TXN;
            int col = e - r * F_TXN;
            a[j] = (unsigned)(r * LROW + col);
        }
        wa0[i] = a[0] | (a[1] << 16);
        wa1[i] = a[2] | (a[3] << 16);
    }

    // ---- zero never-written cols 371..383 (read at s=11; B=0 there) ----
    for (int z = t; z < 2 * SLAB_ROWS * 13; z += 256) {
        int b  = z / (SLAB_ROWS * 13);
        int rm = z - b * (SLAB_ROWS * 13);
        int r  = rm / 13;
        int cc = rm - r * 13;
        Alds[b * SLAB_SHORTS + r * LROW + F_TXN + cc] = 0;
    }

    f32x4 arA[6], arB[6];

    auto gload = [&](f32x4 (&ar)[6], int sl) {
        size_t S0 = (size_t)sl * SLAB_F32;   // 16B-aligned, exactly 1484 chunks
        #pragma unroll
        for (int i = 0; i < 6; ++i)
            if (sval[i])
                ar[i] = *reinterpret_cast<const f32x4*>(feats + S0 + (size_t)(i * 256 + t) * 4);
    };
    auto swrite = [&](int buf, const f32x4 (&ar)[6]) {
        unsigned short* dst = Alds + buf * SLAB_SHORTS;
        #pragma unroll
        for (int i = 0; i < 6; ++i)
            if (sval[i]) {
                unsigned lo = cvt_pk(ar[i][0], ar[i][1]);
                unsigned hi = cvt_pk(ar[i][2], ar[i][3]);
                dst[wa0[i] & 0xffffu] = (unsigned short)lo;
                dst[wa0[i] >> 16]     = (unsigned short)(lo >> 16);
                dst[wa1[i] & 0xffffu] = (unsigned short)hi;
                dst[wa1[i] >> 16]     = (unsigned short)(hi >> 16);
            }
    };

    const int bid = blockIdx.x;
    int sl  = bid;
    int cur = 0;

    // prologue: LDS[0] = slab bid; arA = slab bid+P in flight
    gload(arA, sl);
    swrite(0, arA);
    gload(arA, CLSLAB(sl + PBLK));
    __syncthreads();

    auto iter = [&](const f32x4 (&pend)[6], f32x4 (&tgt)[6]) {
        gload(tgt, CLSLAB(sl + 2 * PBLK));        // keep >=6 loads outstanding always
        __builtin_amdgcn_sched_barrier(0);        // don't sink below the vmcnt wait

        f32x4 acc0 = f32x4{0.f, 0.f, 0.f, 0.f};
        f32x4 acc1 = f32x4{0.f, 0.f, 0.f, 0.f};
        const unsigned short* Ar = Alds + cur * SLAB_SHORTS + r16 * LROW;
        #pragma unroll
        for (int s = 0; s < NSTEP; ++s) {         // conflict-free b128 reads
            bf16x8 af = *reinterpret_cast<const bf16x8*>(Ar + s * 32 + kg * 8);
            acc0 = __builtin_amdgcn_mfma_f32_16x16x32_bf16(af, Bf0[s].v, acc0, 0, 0, 0);
            acc1 = __builtin_amdgcn_mfma_f32_16x16x32_bf16(af, Bf1[s].v, acc1, 0, 0, 0);
        }

        swrite(cur ^ 1, pend);                    // waits only pend's (older) loads

        long R0 = (long)sl * SLAB_ROWS + kg * 4;  // NT C-stores fly across the barrier
        #pragma unroll
        for (int j = 0; j < 4; ++j) {
            float* o = out + (OUT_TXN_BASE + R0 + j) * HID;
            __builtin_nontemporal_store(acc0[j] + bv0, o + c0);
            __builtin_nontemporal_store(acc1[j] + bv1, o + c0 + 16);
        }

        asm volatile("s_waitcnt lgkmcnt(0)" ::: "memory");   // LDS writes visible
        __builtin_amdgcn_s_barrier();             // no vmcnt drain
        __builtin_amdgcn_sched_barrier(0);
        cur ^= 1;
        sl  += PBLK;
    };

    while (sl < NSLAB) {
        iter(arA, arB);
        if (sl >= NSLAB) break;
        iter(arB, arA);
    }
}

extern "C" void kernel_launch(void* const* d_in, const int* in_sizes, int n_in,
                              void* d_out, int out_size, void* d_ws, size_t ws_size,
                              hipStream_t stream) {
    const float* cat_tables    = (const float*)d_in[0];
    const float* cont_w        = (const float*)d_in[1];
    const float* cont_b        = (const float*)d_in[2];
    const float* txn_w         = (const float*)d_in[3];
    const float* txn_b         = (const float*)d_in[4];
    const float* txn_feats     = (const float*)d_in[5];
    const float* cont_values   = (const float*)d_in[6];
    const int*   cat_type_ids  = (const int*)d_in[7];
    const int*   cat_value_ids = (const int*)d_in[8];
    const int*   cont_type_ids = (const int*)d_in[9];
    float* out = (float*)d_out;

    txn_persist_kernel<<<PBLK, 256, 0, stream>>>(txn_feats, txn_w, txn_b, out);
    catcont_kernel<<<CAT_BLOCKS + CONT_BLOCKS, 256, 0, stream>>>(
        cat_tables, cat_type_ids, cat_value_ids,
        cont_w, cont_b, cont_values, cont_type_ids, out);
}

// Round 19
// 83.603 us; speedup vs baseline: 1.4390x; 1.0090x over previous
//
#include <hip/hip_runtime.h>

#define HID    128
#define VOCAB  1000
#define N_CAT  200000
#define N_CONT 150000
#define N_TXN  150000
#define F_TXN  371
#define NSTEP  12                            // 12*32 = 384 >= 371
#define OUT_TXN_BASE (N_CAT + N_CONT)

#define SLAB_ROWS   32
#define SLAB_F32    (SLAB_ROWS * F_TXN)      // 11872 floats = 2968 x 16B chunks
#define SLAB_CHUNKS (SLAB_F32 / 4)           // 2968
#define LROW        392                      // LDS row stride (shorts), odd 16B-chunk count
#define SLAB_SHORTS (SLAB_ROWS * LROW)       // 12544 shorts = 25088 B
#define NSLAB       ((N_TXN + SLAB_ROWS - 1) / SLAB_ROWS)   // 4688 (last slab partial)
#define A_ELEMS     ((size_t)N_TXN * F_TXN)  // 55,650,000
#define PBLK        512                      // 2 blocks/CU (proven best)

typedef __attribute__((ext_vector_type(4))) float f32x4;
typedef __attribute__((ext_vector_type(8))) short bf16x8;

__device__ __forceinline__ unsigned cvt_pk(float lo, float hi) {
    unsigned r;
    asm("v_cvt_pk_bf16_f32 %0, %1, %2" : "=v"(r) : "v"(lo), "v"(hi));
    return r;
}

union BFrag { bf16x8 v; unsigned u[4]; };

// ---- fused cat gather + cont linear; NT stores keep out-stream out of L3 ----
#define CAT_BLOCKS  (N_CAT / 8)
#define CONT_BLOCKS (N_CONT / 8)
__global__ __launch_bounds__(256) void catcont_kernel(
    const float* __restrict__ tables, const int* __restrict__ tids, const int* __restrict__ vids,
    const float* __restrict__ w, const float* __restrict__ b,
    const float* __restrict__ vals, const int* __restrict__ ctids,
    float* __restrict__ out)
{
    int bid = blockIdx.x;
    if (bid < CAT_BLOCKS) {
        int tid = bid * 256 + threadIdx.x;
        int row = tid >> 5;
        int h   = (tid & 31) << 2;
        long src = ((long)tids[row] * VOCAB + vids[row]) * HID + h;
        f32x4 v = *reinterpret_cast<const f32x4*>(tables + src);
        __builtin_nontemporal_store(v, reinterpret_cast<f32x4*>(out + (long)row * HID + h));
    } else {
        int tid = (bid - CAT_BLOCKS) * 256 + threadIdx.x;
        int row = tid >> 5;
        int h   = (tid & 31) << 2;
        int t   = ctids[row];
        float v = vals[row];
        f32x4 wv = *reinterpret_cast<const f32x4*>(w + t * HID + h);
        f32x4 bv = *reinterpret_cast<const f32x4*>(b + t * HID + h);
        f32x4 r  = v * wv + bv;
        __builtin_nontemporal_store(r, reinterpret_cast<f32x4*>(out + (long)(N_CAT + row) * HID + h));
    }
}

// ---- persistent txn GEMM: 32-row slabs (half the iterations), inline B-build,
//      depth-1 reg prefetch, dbuf bf16 LDS, NT C-stores ----
__global__ __launch_bounds__(256) void txn_persist_kernel(
    const float* __restrict__ feats, const float* __restrict__ txn_w,
    const float* __restrict__ bias, float* __restrict__ out)
{
    __shared__ __align__(16) unsigned short Alds[2 * SLAB_SHORTS];   // 50176 B

    const int t    = threadIdx.x;
    const int lane = t & 63;
    const int w    = t >> 6;
    const int r16  = lane & 15;
    const int kg   = lane >> 4;

    // ---- B fragments built inline from txn_w (f32, L2-hot), once per block ----
    BFrag Bf0[NSTEP], Bf1[NSTEP];
    const int c0 = w * 32 + r16, c1 = c0 + 16;
    const float bv0 = bias[c0], bv1 = bias[c1];
    #pragma unroll
    for (int s = 0; s < NSTEP; ++s) {
        #pragma unroll
        for (int h = 0; h < 4; ++h) {
            int k = s * 32 + kg * 8 + h * 2;
            float w0 = (k     < F_TXN) ? txn_w[(long)k * HID + c0]       : 0.f;
            float w1 = (k + 1 < F_TXN) ? txn_w[(long)(k + 1) * HID + c0] : 0.f;
            Bf0[s].u[h] = cvt_pk(w0, w1);
            float x0 = (k     < F_TXN) ? txn_w[(long)k * HID + c1]       : 0.f;
            float x1 = (k + 1 < F_TXN) ? txn_w[(long)(k + 1) * HID + c1] : 0.f;
            Bf1[s].u[h] = cvt_pk(x0, x1);
        }
    }

    // ---- staging geometry: thread t owns 16B chunks q = i*256+t, i<12 ----
    bool sval[12];
    unsigned wa0[12], wa1[12];               // packed LDS short-addresses
    #pragma unroll
    for (int i = 0; i < 12; ++i) {
        int q = i * 256 + t;
        sval[i] = (q < SLAB_CHUNKS);
        int qq = sval[i] ? q : 0;
        unsigned a[4];
        #pragma unroll
        for (int j = 0; j < 4; ++j) {
            int e   = qq * 4 + j;            // float index within slab
            int r   = e / F_TXN;
            int col = e - r * F_TXN;
            a[j] = (unsigned)(r * LROW + col);
        }
        wa0[i] = a[0] | (a[1] << 16);
        wa1[i] = a[2] | (a[3] << 16);
    }

    // ---- zero never-written cols 371..383 (read at s=11; B=0 there) ----
    for (int z = t; z < 2 * SLAB_ROWS * 13; z += 256) {
        int b  = z / (SLAB_ROWS * 13);
        int rm = z - b * (SLAB_ROWS * 13);
        int r  = rm / 13;
        int cc = rm - r * 13;
        Alds[b * SLAB_SHORTS + r * LROW + F_TXN + cc] = 0;
    }

    f32x4 ar[12];

    auto gload = [&](int sl) {
        size_t S0 = (size_t)sl * SLAB_F32;
        #pragma unroll
        for (int i = 0; i < 12; ++i)
            if (sval[i]) {
                size_t ge = S0 + (size_t)(i * 256 + t) * 4;
                if (ge > A_ELEMS - 4) ge = A_ELEMS - 4;   // partial last slab clamp
                ar[i] = *reinterpret_cast<const f32x4*>(feats + ge);
            }
    };
    auto swrite = [&](int buf) {
        unsigned short* dst = Alds + buf * SLAB_SHORTS;
        #pragma unroll
        for (int i = 0; i < 12; ++i)
            if (sval[i]) {
                unsigned lo = cvt_pk(ar[i][0], ar[i][1]);
                unsigned hi = cvt_pk(ar[i][2], ar[i][3]);
                dst[wa0[i] & 0xffffu] = (unsigned short)lo;
                dst[wa0[i] >> 16]     = (unsigned short)(lo >> 16);
                dst[wa1[i] & 0xffffu] = (unsigned short)hi;
                dst[wa1[i] >> 16]     = (unsigned short)(hi >> 16);
            }
    };

    const int bid = blockIdx.x;
    gload(bid);
    swrite(0);
    __syncthreads();

    int cur = 0;
    #pragma unroll 1
    for (int sl = bid; sl < NSLAB; sl += PBLK) {
        int  nxt      = sl + PBLK;
        bool have_nxt = (nxt < NSLAB);
        if (have_nxt) gload(nxt);             // 12 loads fly under this slab's compute
        __builtin_amdgcn_sched_barrier(0);

        f32x4 acc00 = f32x4{0.f,0.f,0.f,0.f}, acc01 = f32x4{0.f,0.f,0.f,0.f};
        f32x4 acc10 = f32x4{0.f,0.f,0.f,0.f}, acc11 = f32x4{0.f,0.f,0.f,0.f};
        const unsigned short* Ar0 = Alds + cur * SLAB_SHORTS + r16 * LROW;
        const unsigned short* Ar1 = Ar0 + 16 * LROW;
        #pragma unroll
        for (int s = 0; s < NSTEP; ++s) {     // conflict-free b128 reads
            bf16x8 af0 = *reinterpret_cast<const bf16x8*>(Ar0 + s * 32 + kg * 8);
            bf16x8 af1 = *reinterpret_cast<const bf16x8*>(Ar1 + s * 32 + kg * 8);
            acc00 = __builtin_amdgcn_mfma_f32_16x16x32_bf16(af0, Bf0[s].v, acc00, 0, 0, 0);
            acc01 = __builtin_amdgcn_mfma_f32_16x16x32_bf16(af0, Bf1[s].v, acc01, 0, 0, 0);
            acc10 = __builtin_amdgcn_mfma_f32_16x16x32_bf16(af1, Bf0[s].v, acc10, 0, 0, 0);
            acc11 = __builtin_amdgcn_mfma_f32_16x16x32_bf16(af1, Bf1[s].v, acc11, 0, 0, 0);
        }

        if (have_nxt) swrite(cur ^ 1);        // waits only this iter's 12 loads

        long R0 = (long)sl * SLAB_ROWS + kg * 4;   // NT stores fly across the barrier
        #pragma unroll
        for (int j = 0; j < 4; ++j) {
            long r0 = R0 + j, r1 = R0 + 16 + j;
            if (r0 < N_TXN) {
                float* o = out + (OUT_TXN_BASE + r0) * HID;
                __builtin_nontemporal_store(acc00[j] + bv0, o + c0);
                __builtin_nontemporal_store(acc01[j] + bv1, o + c0 + 16);
            }
            if (r1 < N_TXN) {
                float* o = out + (OUT_TXN_BASE + r1) * HID;
                __builtin_nontemporal_store(acc10[j] + bv0, o + c0);
                __builtin_nontemporal_store(acc11[j] + bv1, o + c0 + 16);
            }
        }

        asm volatile("s_waitcnt lgkmcnt(0)" ::: "memory");   // LDS writes visible
        __builtin_amdgcn_s_barrier();          // no vmcnt drain
        __builtin_amdgcn_sched_barrier(0);
        cur ^= 1;
    }
}

extern "C" void kernel_launch(void* const* d_in, const int* in_sizes, int n_in,
                              void* d_out, int out_size, void* d_ws, size_t ws_size,
                              hipStream_t stream) {
    const float* cat_tables    = (const float*)d_in[0];
    const float* cont_w        = (const float*)d_in[1];
    const float* cont_b        = (const float*)d_in[2];
    const float* txn_w         = (const float*)d_in[3];
    const float* txn_b         = (const float*)d_in[4];
    const float* txn_feats     = (const float*)d_in[5];
    const float* cont_values   = (const float*)d_in[6];
    const int*   cat_type_ids  = (const int*)d_in[7];
    const int*   cat_value_ids = (const int*)d_in[8];
    const int*   cont_type_ids = (const int*)d_in[9];
    float* out = (float*)d_out;

    txn_persist_kernel<<<PBLK, 256, 0, stream>>>(txn_feats, txn_w, txn_b, out);
    catcont_kernel<<<CAT_BLOCKS + CONT_BLOCKS, 256, 0, stream>>>(
        cat_tables, cat_type_ids, cat_value_ids,
        cont_w, cont_b, cont_values, cont_type_ids, out);
}